// Round 3
// baseline (1018.452 us; speedup 1.0000x reference)
//
#include <hip/hip_runtime.h>
#include <hip/hip_bf16.h>
#include <stdint.h>

typedef __hip_bfloat16 bf16;
typedef short bf16x8 __attribute__((ext_vector_type(8)));
typedef float f32x4 __attribute__((ext_vector_type(4)));

typedef __attribute__((address_space(1))) const unsigned int as1_uint;
typedef __attribute__((address_space(3))) unsigned int as3_uint;

__device__ __forceinline__ void async_copy16(const void* g, void* l) {
    __builtin_amdgcn_global_load_lds((as1_uint*)g, (as3_uint*)l, 16, 0, 0);
}

__device__ __forceinline__ float b2f(unsigned short u) {
    union { unsigned int i; float f; } c; c.i = ((unsigned int)u) << 16; return c.f;
}
__device__ __forceinline__ unsigned short f2b(float f) {
    union { float f; unsigned int i; } c; c.f = f;
    unsigned int i = c.i;
    i += 0x7fffu + ((i >> 16) & 1u);   // round-to-nearest-even
    return (unsigned short)(i >> 16);
}

// ---------------------------------------------------------------------------
// f32 -> bf16 conversion (weights). 8 elements/thread.
// ---------------------------------------------------------------------------
__global__ __launch_bounds__(256)
void cvt_kernel(const float* __restrict__ in, bf16* __restrict__ out)
{
    const int i = (blockIdx.x * 256 + threadIdx.x) * 8;
    const float4 a = *(const float4*)(in + i);
    const float4 b = *(const float4*)(in + i + 4);
    union { uint4 v; unsigned short s[8]; } u;
    u.s[0] = f2b(a.x); u.s[1] = f2b(a.y); u.s[2] = f2b(a.z); u.s[3] = f2b(a.w);
    u.s[4] = f2b(b.x); u.s[5] = f2b(b.y); u.s[6] = f2b(b.z); u.s[7] = f2b(b.w);
    *(uint4*)((unsigned short*)out + i) = u.v;
}

// ---------------------------------------------------------------------------
// LayerNorm: one wave per row of 512; block = 4 rows. f32 in, bf16 out.
// ---------------------------------------------------------------------------
__global__ __launch_bounds__(256)
void ln_kernel(const float* __restrict__ x, const float* __restrict__ g,
               const float* __restrict__ beta, bf16* __restrict__ out)
{
    const int w = threadIdx.x >> 6, l = threadIdx.x & 63;
    const int n = blockIdx.x * 4 + w;

    const float* xr = x + (size_t)n * 512 + l * 8;
    const float4 a = *(const float4*)xr;
    const float4 b = *(const float4*)(xr + 4);
    float f[8] = {a.x, a.y, a.z, a.w, b.x, b.y, b.z, b.w};

    float s = 0.f, q = 0.f;
#pragma unroll
    for (int i = 0; i < 8; ++i) { s += f[i]; q += f[i] * f[i]; }
#pragma unroll
    for (int o = 32; o > 0; o >>= 1) { s += __shfl_xor(s, o); q += __shfl_xor(q, o); }
    const float mean = s * (1.f / 512.f);
    const float var  = q * (1.f / 512.f) - mean * mean;
    const float rstd = rsqrtf(var + 1e-5f);

    const float4 g0 = *(const float4*)(g + l * 8);
    const float4 g1 = *(const float4*)(g + l * 8 + 4);
    const float4 b0 = *(const float4*)(beta + l * 8);
    const float4 b1 = *(const float4*)(beta + l * 8 + 4);
    const float gg[8] = {g0.x,g0.y,g0.z,g0.w,g1.x,g1.y,g1.z,g1.w};
    const float bb[8] = {b0.x,b0.y,b0.z,b0.w,b1.x,b1.y,b1.z,b1.w};

    union { uint4 v; unsigned short s[8]; } o;
#pragma unroll
    for (int i = 0; i < 8; ++i)
        o.s[i] = f2b((f[i] - mean) * rstd * gg[i] + bb[i]);
    *(uint4*)((unsigned short*)out + (size_t)n * 512 + l * 8) = o.v;
}

// ---------------------------------------------------------------------------
// Per-node attention over heads. qkv [n][1536] = q(8x64),k(8x64),v(8x64).
// One wave per node; lane (h=l>>3, g=l&7) owns score s[h][g]. bf16 in/out.
// ---------------------------------------------------------------------------
__global__ __launch_bounds__(256)
void attn_kernel(const bf16* __restrict__ qkv, bf16* __restrict__ out)
{
    __shared__ unsigned short sm[4][1536];
    const int w = threadIdx.x >> 6, l = threadIdx.x & 63;
    const int n = blockIdx.x * 4 + w;

    const uint4* src = (const uint4*)((const unsigned short*)qkv + (size_t)n * 1536);
    uint4* dst = (uint4*)sm[w];
#pragma unroll
    for (int i = 0; i < 3; ++i) dst[i * 64 + l] = src[i * 64 + l];
    __syncthreads();

    const int h = l >> 3, gi = l & 7;
    const unsigned short* qrow = sm[w] + h * 64;
    const unsigned short* krow = sm[w] + 512 + gi * 64;
    float s = 0.f;
#pragma unroll
    for (int jj = 0; jj < 8; ++jj) {
        union { uint4 v; unsigned short s8[8]; } qa, ka;
        qa.v = *(const uint4*)(qrow + jj * 8);
        ka.v = *(const uint4*)(krow + jj * 8);
#pragma unroll
        for (int j = 0; j < 8; ++j) s += b2f(qa.s8[j]) * b2f(ka.s8[j]);
    }
    s *= 0.125f;   // 1/sqrt(64)

    float m = s;
#pragma unroll
    for (int o = 1; o < 8; o <<= 1) m = fmaxf(m, __shfl_xor(m, o));
    float e = __expf(s - m);
    float d = e;
#pragma unroll
    for (int o = 1; o < 8; o <<= 1) d += __shfl_xor(d, o);
    const float p = e / d;

    float acc[8];
#pragma unroll
    for (int j = 0; j < 8; ++j) acc[j] = 0.f;
    const int j8 = (l & 7) * 8;
#pragma unroll
    for (int gg = 0; gg < 8; ++gg) {
        const float pg = __shfl(p, (l & 56) | gg);
        union { uint4 v; unsigned short s8[8]; } va;
        va.v = *(const uint4*)(sm[w] + 1024 + gg * 64 + j8);
#pragma unroll
        for (int j = 0; j < 8; ++j) acc[j] += pg * b2f(va.s8[j]);
    }
    union { uint4 v; unsigned short s8[8]; } o;
#pragma unroll
    for (int j = 0; j < 8; ++j) o.s8[j] = f2b(acc[j]);
    *(uint4*)((unsigned short*)out + (size_t)n * 512 + h * 64 + j8) = o.v;
}

// ---------------------------------------------------------------------------
// GEMM  C = A[M][K] * B^T (+f32 bias, +f32 res, relu).
// 128x128 tile, BK=32, 256 thr = 4 waves (2x2), wave tile 64x64.
// 3-slot LDS ring (48 KiB -> 3 blocks/CU = 12 waves/CU), prefetch-2,
// counted vmcnt(4) (never drains mid-loop), ONE barrier per K-step.
// XOR chunk swizzle on staging src + ds_read (verified conflict-free r1/r2),
// setprio around MFMA, bijective XCD block swizzle.
// QKV fusion: column block selects B0/B1/B2 via colBase/Nper.
// ---------------------------------------------------------------------------
#define EPI_PLAIN 0
#define EPI_RES   1
#define EPI_RELU  2

template<int MODE>
__global__ __launch_bounds__(256, 3)
void gemm_bt(const bf16* __restrict__ A,
             const bf16* __restrict__ B0, const bf16* __restrict__ B1,
             const bf16* __restrict__ B2,
             const float* __restrict__ bias0, const float* __restrict__ bias1,
             const float* __restrict__ bias2,
             const float* __restrict__ res,
             void* __restrict__ C,
             int K, int Nper, int ldc)
{
    __shared__ bf16 As[3][4096];   // 3 slots x (128 rows x 32 k) = 24 KiB
    __shared__ bf16 Bs[3][4096];   // 24 KiB

    const int tid = threadIdx.x;
    const int w = tid >> 6, l = tid & 63;

    // T1: bijective XCD-aware remap of the linear block id (m204 form).
    const int nbx = gridDim.x;
    const int nwg = nbx * (int)gridDim.y;
    int lid = blockIdx.y * nbx + blockIdx.x;
    {
        const int q = nwg >> 3, r = nwg & 7;
        const int xcd = lid & 7, idx = lid >> 3;
        lid = (xcd < r ? xcd * (q + 1) : r * (q + 1) + (xcd - r) * q) + idx;
    }
    const int bx = lid % nbx, by = lid / nbx;

    const int rowBase = by * 128;
    const int colBase = bx * 128;
    const int sel = colBase / Nper;
    const bf16*  B    = (sel == 0) ? B0 : (sel == 1) ? B1 : B2;
    const float* bias = (sel == 0) ? bias0 : (sel == 1) ? bias1 : bias2;
    const int colInB = colBase - sel * Nper;

    const bf16* Ag = A + (size_t)rowBase * K;
    const bf16* Bg = B + (size_t)colInB * K;

    const int wr = w >> 1, wc = w & 1;             // 2 x 2 wave grid
    const int ml = l & 15;
    // swizzled read chunk: global k-chunk (l>>4) lives at LDS col (l>>4)^((row>>1)&3)
    const int ac = (((l >> 4) ^ ((ml >> 1) & 3)) << 3);

    // Stage one 128x32 K-tile of A and B into ring slot (4 gload_lds/thread).
    // LDS dest linear (wave-uniform base + lane*16); source chunk pre-swizzled
    // with the same involution the reads use (rule #21).
    auto stage = [&](int t, int slot) {
        const int lr = l >> 2, lc = l & 3;
        const int c = lc ^ ((lr >> 1) & 3);        // swizzled src chunk
#pragma unroll
        for (int i = 0; i < 2; ++i) {
            const int base = w * 32 + i * 16;      // 16-row group
            const size_t go = (size_t)(base + lr) * K + (t << 5) + (c << 3);
            async_copy16(Ag + go, &As[slot][base << 5]);
            async_copy16(Bg + go, &Bs[slot][base << 5]);
        }
    };

    f32x4 acc[4][4];
#pragma unroll
    for (int i = 0; i < 4; ++i)
#pragma unroll
        for (int j = 0; j < 4; ++j) acc[i][j] = (f32x4)(0.f);

    const int NT = K >> 5;   // K-tiles of 32 (min 16 here)

    // prologue: tiles 0,1 in flight (8 loads/thread); wait tile 0 only.
    stage(0, 0); stage(1, 1);
    asm volatile("s_waitcnt vmcnt(4)" ::: "memory");
    __builtin_amdgcn_s_barrier();

    int slot = 0, pslot = 2;
    for (int t = 0; t < NT; ++t) {
        // prefetch tile t+2 into slot (t+2)%3 == (t-1)%3: last read at iter
        // t-1, completed before that iteration's end barrier -> race-free.
        if (t + 2 < NT) stage(t + 2, pslot);

        const bf16* Ac = &As[slot][0];
        const bf16* Bc = &Bs[slot][0];
        bf16x8 af[4], bfr[4];
#pragma unroll
        for (int mi = 0; mi < 4; ++mi)
            af[mi] = *(const bf16x8*)(Ac + (((wr << 6) + (mi << 4) + ml) << 5) + ac);
#pragma unroll
        for (int ni = 0; ni < 4; ++ni)
            bfr[ni] = *(const bf16x8*)(Bc + (((wc << 6) + (ni << 4) + ml) << 5) + ac);

        __builtin_amdgcn_s_setprio(1);
#pragma unroll
        for (int mi = 0; mi < 4; ++mi)
#pragma unroll
            for (int ni = 0; ni < 4; ++ni)
                acc[mi][ni] = __builtin_amdgcn_mfma_f32_16x16x32_bf16(
                    af[mi], bfr[ni], acc[mi][ni], 0, 0, 0);
        __builtin_amdgcn_s_setprio(0);

        // counted vmcnt: tile t+1 landed (4 oldest), tile t+2 stays in flight.
        if (t + 2 < NT)       asm volatile("s_waitcnt vmcnt(4)" ::: "memory");
        else if (t == NT - 2) asm volatile("s_waitcnt vmcnt(0)" ::: "memory");
        if (t < NT - 1) __builtin_amdgcn_s_barrier();

        slot  = (slot  == 2) ? 0 : slot + 1;
        pslot = (pslot == 2) ? 0 : pslot + 1;
    }

    // epilogue: C/D layout col=lane&15, row=(lane>>4)*4+reg
    float bv[4];
#pragma unroll
    for (int ni = 0; ni < 4; ++ni)
        bv[ni] = bias[colInB + (wc << 6) + (ni << 4) + ml];

#pragma unroll
    for (int mi = 0; mi < 4; ++mi) {
#pragma unroll
        for (int r4 = 0; r4 < 4; ++r4) {
            const int row = rowBase + (wr << 6) + (mi << 4) + ((l >> 4) << 2) + r4;
            const size_t rowoff = (size_t)row * ldc;
#pragma unroll
            for (int ni = 0; ni < 4; ++ni) {
                const int gcol = colBase + (wc << 6) + (ni << 4) + ml;
                float v = acc[mi][ni][r4] + bv[ni];
                if (MODE == EPI_RELU) v = fmaxf(v, 0.f);
                if (MODE == EPI_RES) {
                    v += res[rowoff + gcol];
                    ((float*)C)[rowoff + gcol] = v;          // f32 output
                } else {
                    ((unsigned short*)C)[rowoff + gcol] = f2b(v);  // bf16
                }
            }
        }
    }
}

// ---------------------------------------------------------------------------
extern "C" void kernel_launch(void* const* d_in, const int* in_sizes, int n_in,
                              void* d_out, int out_size, void* d_ws, size_t ws_size,
                              hipStream_t stream)
{
    const float* x   = (const float*)d_in[0];
    const float* Wq  = (const float*)d_in[1];
    const float* bq  = (const float*)d_in[2];
    const float* Wk  = (const float*)d_in[3];
    const float* bk  = (const float*)d_in[4];
    const float* Wv  = (const float*)d_in[5];
    const float* bv  = (const float*)d_in[6];
    const float* Wo  = (const float*)d_in[7];
    const float* bo  = (const float*)d_in[8];
    const float* W1  = (const float*)d_in[9];
    const float* b1  = (const float*)d_in[10];
    const float* W2  = (const float*)d_in[11];
    const float* b2  = (const float*)d_in[12];
    const float* g1  = (const float*)d_in[13];
    const float* be1 = (const float*)d_in[14];
    const float* g2  = (const float*)d_in[15];
    const float* be2 = (const float*)d_in[16];

    const int N = 65536;

    // ws layout:
    //   [0, 6 MiB)    bf16 weights: Wq,Wk,Wv,Wo (512x512), W1 (2048x512), W2 (512x2048)
    //   [6, 70 MiB)   t64: h -> attnout -> h2   (N x 512 bf16)
    //   [70 MiB, ..)  chunk buffer: qkv [Nc][1536] / ff1 [Nc][2048] bf16
    bf16* Wqb = (bf16*)d_ws;
    bf16* Wkb = Wqb + 262144;
    bf16* Wvb = Wkb + 262144;
    bf16* Wob = Wvb + 262144;
    bf16* W1b = Wob + 262144;
    bf16* W2b = W1b + 1048576;
    const size_t wts_bytes = 6ull * 1024 * 1024;
    bf16* t64 = (bf16*)((char*)d_ws + wts_bytes);
    const size_t t64_bytes = (size_t)N * 512 * 2;   // 64 MiB
    bf16* cb  = (bf16*)((char*)d_ws + wts_bytes + t64_bytes);
    const size_t used = wts_bytes + t64_bytes;
    const size_t avail = ws_size > used ? ws_size - used : 0;
    // Cap Nc at 32768: keeps qkv (96 MB) / ff1 (128 MB) chunks mostly
    // L3-resident and makes every gemm grid a whole multiple of 256 CUs.
    int Nc = 32768;
    while (Nc > 256 && (size_t)Nc * 4096 > avail) Nc >>= 1;

    float* x2 = (float*)d_out;
    dim3 blk(256);

    // 0. convert weights f32 -> bf16
    cvt_kernel<<<262144 / 2048, blk, 0, stream>>>(Wq, Wqb);
    cvt_kernel<<<262144 / 2048, blk, 0, stream>>>(Wk, Wkb);
    cvt_kernel<<<262144 / 2048, blk, 0, stream>>>(Wv, Wvb);
    cvt_kernel<<<262144 / 2048, blk, 0, stream>>>(Wo, Wob);
    cvt_kernel<<<1048576 / 2048, blk, 0, stream>>>(W1, W1b);
    cvt_kernel<<<1048576 / 2048, blk, 0, stream>>>(W2, W2b);

    // 1. h = LN1(x) -> t64 (bf16)
    ln_kernel<<<N / 4, blk, 0, stream>>>(x, g1, be1, t64);

    // 2+3. per chunk: qkv_c = h_c @ [Wq|Wk|Wv]^T + bias ; attnout_c = attn(qkv_c)
    for (int r0 = 0; r0 < N; r0 += Nc) {
        gemm_bt<EPI_PLAIN><<<dim3(12, Nc / 128), blk, 0, stream>>>(
            t64 + (size_t)r0 * 512, Wqb, Wkb, Wvb, bq, bk, bv, nullptr,
            cb, 512, 512, 1536);
        attn_kernel<<<Nc / 4, blk, 0, stream>>>(cb, t64 + (size_t)r0 * 512);
    }

    // 4. x2 = x + attnout @ Wo^T + bo   -> d_out (f32)
    gemm_bt<EPI_RES><<<dim3(4, N / 128), blk, 0, stream>>>(
        t64, Wob, Wob, Wob, bo, bo, bo, x, x2, 512, 512, 512);

    // 5. h2 = LN2(x2) -> t64 (bf16)
    ln_kernel<<<N / 4, blk, 0, stream>>>(x2, g2, be2, t64);

    // 6+7. per chunk: ff1_c = relu(h2_c @ W1^T + b1);
    //      out_c = x2_c + ff1_c @ W2^T + b2  (in-place on d_out, f32)
    for (int r0 = 0; r0 < N; r0 += Nc) {
        gemm_bt<EPI_RELU><<<dim3(16, Nc / 128), blk, 0, stream>>>(
            t64 + (size_t)r0 * 512, W1b, W1b, W1b, b1, b1, b1, nullptr,
            cb, 512, 2048, 2048);
        gemm_bt<EPI_RES><<<dim3(4, Nc / 128), blk, 0, stream>>>(
            cb, W2b, W2b, W2b, b2, b2, b2, x2 + (size_t)r0 * 512,
            x2 + (size_t)r0 * 512, 2048, 512, 512);
    }
}

// Round 4
// 925.451 us; speedup vs baseline: 1.1005x; 1.1005x over previous
//
#include <hip/hip_runtime.h>
#include <hip/hip_bf16.h>
#include <stdint.h>

typedef __hip_bfloat16 bf16;
typedef short bf16x8 __attribute__((ext_vector_type(8)));
typedef float f32x4 __attribute__((ext_vector_type(4)));

typedef __attribute__((address_space(1))) const unsigned int as1_uint;
typedef __attribute__((address_space(3))) unsigned int as3_uint;

__device__ __forceinline__ void async_copy16(const void* g, void* l) {
    __builtin_amdgcn_global_load_lds((as1_uint*)g, (as3_uint*)l, 16, 0, 0);
}

__device__ __forceinline__ float b2f(unsigned short u) {
    union { unsigned int i; float f; } c; c.i = ((unsigned int)u) << 16; return c.f;
}
__device__ __forceinline__ unsigned short f2b(float f) {
    union { float f; unsigned int i; } c; c.f = f;
    unsigned int i = c.i;
    i += 0x7fffu + ((i >> 16) & 1u);   // round-to-nearest-even
    return (unsigned short)(i >> 16);
}

// ---------------------------------------------------------------------------
// f32 -> bf16 conversion (weights). 8 elements/thread.
// ---------------------------------------------------------------------------
__global__ __launch_bounds__(256)
void cvt_kernel(const float* __restrict__ in, bf16* __restrict__ out)
{
    const int i = (blockIdx.x * 256 + threadIdx.x) * 8;
    const float4 a = *(const float4*)(in + i);
    const float4 b = *(const float4*)(in + i + 4);
    union { uint4 v; unsigned short s[8]; } u;
    u.s[0] = f2b(a.x); u.s[1] = f2b(a.y); u.s[2] = f2b(a.z); u.s[3] = f2b(a.w);
    u.s[4] = f2b(b.x); u.s[5] = f2b(b.y); u.s[6] = f2b(b.z); u.s[7] = f2b(b.w);
    *(uint4*)((unsigned short*)out + i) = u.v;
}

// ---------------------------------------------------------------------------
// LayerNorm: one wave per row of 512; block = 4 rows. f32 in, bf16 out.
// ---------------------------------------------------------------------------
__global__ __launch_bounds__(256)
void ln_kernel(const float* __restrict__ x, const float* __restrict__ g,
               const float* __restrict__ beta, bf16* __restrict__ out)
{
    const int w = threadIdx.x >> 6, l = threadIdx.x & 63;
    const int n = blockIdx.x * 4 + w;

    const float* xr = x + (size_t)n * 512 + l * 8;
    const float4 a = *(const float4*)xr;
    const float4 b = *(const float4*)(xr + 4);
    float f[8] = {a.x, a.y, a.z, a.w, b.x, b.y, b.z, b.w};

    float s = 0.f, q = 0.f;
#pragma unroll
    for (int i = 0; i < 8; ++i) { s += f[i]; q += f[i] * f[i]; }
#pragma unroll
    for (int o = 32; o > 0; o >>= 1) { s += __shfl_xor(s, o); q += __shfl_xor(q, o); }
    const float mean = s * (1.f / 512.f);
    const float var  = q * (1.f / 512.f) - mean * mean;
    const float rstd = rsqrtf(var + 1e-5f);

    const float4 g0 = *(const float4*)(g + l * 8);
    const float4 g1 = *(const float4*)(g + l * 8 + 4);
    const float4 b0 = *(const float4*)(beta + l * 8);
    const float4 b1 = *(const float4*)(beta + l * 8 + 4);
    const float gg[8] = {g0.x,g0.y,g0.z,g0.w,g1.x,g1.y,g1.z,g1.w};
    const float bb[8] = {b0.x,b0.y,b0.z,b0.w,b1.x,b1.y,b1.z,b1.w};

    union { uint4 v; unsigned short s[8]; } o;
#pragma unroll
    for (int i = 0; i < 8; ++i)
        o.s[i] = f2b((f[i] - mean) * rstd * gg[i] + bb[i]);
    *(uint4*)((unsigned short*)out + (size_t)n * 512 + l * 8) = o.v;
}

// ---------------------------------------------------------------------------
// Per-node attention over heads. qkv [n][1536] = q(8x64),k(8x64),v(8x64).
// One wave per node; lane (h=l>>3, g=l&7) owns score s[h][g]. bf16 in/out.
// ---------------------------------------------------------------------------
__global__ __launch_bounds__(256)
void attn_kernel(const bf16* __restrict__ qkv, bf16* __restrict__ out)
{
    __shared__ unsigned short sm[4][1536];
    const int w = threadIdx.x >> 6, l = threadIdx.x & 63;
    const int n = blockIdx.x * 4 + w;

    const uint4* src = (const uint4*)((const unsigned short*)qkv + (size_t)n * 1536);
    uint4* dst = (uint4*)sm[w];
#pragma unroll
    for (int i = 0; i < 3; ++i) dst[i * 64 + l] = src[i * 64 + l];
    __syncthreads();

    const int h = l >> 3, gi = l & 7;
    const unsigned short* qrow = sm[w] + h * 64;
    const unsigned short* krow = sm[w] + 512 + gi * 64;
    float s = 0.f;
#pragma unroll
    for (int jj = 0; jj < 8; ++jj) {
        union { uint4 v; unsigned short s8[8]; } qa, ka;
        qa.v = *(const uint4*)(qrow + jj * 8);
        ka.v = *(const uint4*)(krow + jj * 8);
#pragma unroll
        for (int j = 0; j < 8; ++j) s += b2f(qa.s8[j]) * b2f(ka.s8[j]);
    }
    s *= 0.125f;   // 1/sqrt(64)

    float m = s;
#pragma unroll
    for (int o = 1; o < 8; o <<= 1) m = fmaxf(m, __shfl_xor(m, o));
    float e = __expf(s - m);
    float d = e;
#pragma unroll
    for (int o = 1; o < 8; o <<= 1) d += __shfl_xor(d, o);
    const float p = e / d;

    float acc[8];
#pragma unroll
    for (int j = 0; j < 8; ++j) acc[j] = 0.f;
    const int j8 = (l & 7) * 8;
#pragma unroll
    for (int gg = 0; gg < 8; ++gg) {
        const float pg = __shfl(p, (l & 56) | gg);
        union { uint4 v; unsigned short s8[8]; } va;
        va.v = *(const uint4*)(sm[w] + 1024 + gg * 64 + j8);
#pragma unroll
        for (int j = 0; j < 8; ++j) acc[j] += pg * b2f(va.s8[j]);
    }
    union { uint4 v; unsigned short s8[8]; } o;
#pragma unroll
    for (int j = 0; j < 8; ++j) o.s8[j] = f2b(acc[j]);
    *(uint4*)((unsigned short*)out + (size_t)n * 512 + h * 64 + j8) = o.v;
}

// ---------------------------------------------------------------------------
// GEMM  C = A[M][K] * B^T (+f32 bias, +f32 res, relu) — m201 8-phase port.
// BM=BN=256, BK=64, 512 thr = 8 waves (2M x 4N), wave tile 128x64.
// LDS: As/Bs [2 slot][2 half][128 rows x 64 k as two 32-k planes] = 128 KiB.
// Each of 8 phases: {ds_read subtile + stage ONE half-tile; barrier;
// lgkmcnt(0); setprio(1); 16 MFMA; setprio(0); barrier}. vmcnt(4) only at
// P4/P8. Staging stream (derived race-free; each stage issues after the
// barrier retiring the target buffer's last reader):
//   P1:A(T1)h1  P2:B(T1)h1  P3:B(T2)h0  P4:B(T2)h1
//   P5:A(T2)h0  P6:A(T2)h1  P7:B(T3)h0  P8:A(T3)h0
// K stored as two 32-k planes per half so the session-verified conflict-free
// XOR chunk swizzle (64 B row stride) applies on both stage-src and ds_read.
// ---------------------------------------------------------------------------
#define EPI_PLAIN 0
#define EPI_RES   1
#define EPI_RELU  2

template<int MODE>
__global__ __launch_bounds__(512, 2)
void gemm_bt(const bf16* __restrict__ A,
             const bf16* __restrict__ B0, const bf16* __restrict__ B1,
             const bf16* __restrict__ B2,
             const float* __restrict__ bias0, const float* __restrict__ bias1,
             const float* __restrict__ bias2,
             const float* __restrict__ res,
             void* __restrict__ C,
             int K, int Nper, int ldc)
{
    __shared__ bf16 As[2][2][8192];   // [slot][half][plane(2)*4096 + row*32 + k]
    __shared__ bf16 Bs[2][2][8192];   // 64 KiB + 64 KiB

    const int tid = threadIdx.x;
    const int w = tid >> 6, l = tid & 63;

    // bijective XCD-aware remap (all grids here are multiples of 8).
    const int nbx = gridDim.x;
    const int nwg = nbx * (int)gridDim.y;
    int lid = blockIdx.y * nbx + blockIdx.x;
    {
        const int q = nwg >> 3, r = nwg & 7;
        const int xcd = lid & 7, idx = lid >> 3;
        lid = (xcd < r ? xcd * (q + 1) : r * (q + 1) + (xcd - r) * q) + idx;
    }
    const int bx = lid % nbx, by = lid / nbx;

    const int rowBase = by * 256;
    const int colBase = bx * 256;
    const int sel = colBase / Nper;
    const bf16*  B    = (sel == 0) ? B0 : (sel == 1) ? B1 : B2;
    const float* bias = (sel == 0) ? bias0 : (sel == 1) ? bias1 : bias2;
    const int colInB = colBase - sel * Nper;

    const bf16* Ag = A + (size_t)rowBase * K;
    const bf16* Bg = B + (size_t)colInB * K;

    const int wr = w >> 2, wc = w & 3;   // 2 x 4 wave grid; wave tile 128x64
    const int ml = l & 15;
    const int kc = l >> 4;                               // 0..3
    const int rdoff = ((kc ^ ((ml >> 1) & 3)) << 3);     // swizzled read chunk

    // stage lane geometry (16 KiB half-tile = 16 wave-chunks of 1 KiB)
    const int s_row = l >> 2;                            // 0..15 row in 16-row grp
    const int s_koff = (((l & 3) ^ ((l >> 3) & 3)) << 3);// swizzled src chunk

    // stage ONE half-tile (2 x global_load_lds per thread)
    auto stA = [&](int t, int half) {
#pragma unroll
        for (int c = 0; c < 2; ++c) {
            const int q = (w << 1) | c;                  // 0..15
            const int p = q >> 3, rr = q & 7;
            const bf16* src = Ag + (size_t)(half * 128 + rr * 16 + s_row) * K
                            + (t << 6) + p * 32 + s_koff;
            async_copy16(src, &As[t & 1][half][q << 9]);
        }
    };
    auto stB = [&](int t, int half) {
#pragma unroll
        for (int c = 0; c < 2; ++c) {
            const int q = (w << 1) | c;
            const int p = q >> 3, rr = q & 7;
            const bf16* src = Bg + (size_t)(half * 128 + rr * 16 + s_row) * K
                            + (t << 6) + p * 32 + s_koff;
            async_copy16(src, &Bs[t & 1][half][q << 9]);
        }
    };

    const int bRow = ((wc & 1) << 6) + ml;   // row base within B half
    const int bHalf = wc >> 1;

    f32x4 acc[8][4];
#pragma unroll
    for (int i = 0; i < 8; ++i)
#pragma unroll
        for (int j = 0; j < 4; ++j) acc[i][j] = (f32x4)(0.f);

    bf16x8 af[4][2], bf[4][2];

#define LDA(SLOT, MI, KS) \
    (*(const bf16x8*)(&As[SLOT][wr][(KS) * 4096 + ((MI) * 16 + ml) * 32 + rdoff]))
#define LDB(SLOT, NI, KS) \
    (*(const bf16x8*)(&Bs[SLOT][bHalf][(KS) * 4096 + (bRow + (NI) * 16) * 32 + rdoff]))

#define MMQ(MG, NG) \
    do { \
        _Pragma("unroll") \
        for (int mi = 0; mi < 4; ++mi) \
        _Pragma("unroll") \
        for (int nj = 0; nj < 2; ++nj) \
        _Pragma("unroll") \
        for (int ks = 0; ks < 2; ++ks) \
            acc[(MG)*4+mi][(NG)*2+nj] = __builtin_amdgcn_mfma_f32_16x16x32_bf16( \
                af[mi][ks], bf[(NG)*2+nj][ks], acc[(MG)*4+mi][(NG)*2+nj], 0, 0, 0); \
    } while (0)

#define SYNC_IN()  do { __builtin_amdgcn_s_barrier(); \
                        __builtin_amdgcn_sched_barrier(0); \
                        asm volatile("s_waitcnt lgkmcnt(0)" ::: "memory"); \
                        __builtin_amdgcn_sched_barrier(0); } while (0)
#define SYNC_OUT() do { __builtin_amdgcn_s_barrier(); \
                        __builtin_amdgcn_sched_barrier(0); } while (0)

    const int NT = K >> 6;   // K-tiles of 64 (8 or 32 here)
    const int NI = NT >> 1;  // iterations of 2 K-tiles

    // prologue: T0 fully + A(1)h0 + B(1)h0  (12 loads/thread)
    stA(0, 0); stA(0, 1); stB(0, 0); stB(0, 1);
    stA(1, 0); stB(1, 0);
    asm volatile("s_waitcnt vmcnt(4)" ::: "memory");
    __builtin_amdgcn_s_barrier();
    __builtin_amdgcn_sched_barrier(0);

    for (int i = 0; i < NI; ++i) {
        const int t1 = 2 * i + 1;
        const bool pf = (t1 + 1 < NT);

        // ---- P1: read T0 af[0-3], bf[0-1]; stage A(T1)h1
#pragma unroll
        for (int mi = 0; mi < 4; ++mi) { af[mi][0] = LDA(0, mi, 0); af[mi][1] = LDA(0, mi, 1); }
#pragma unroll
        for (int nj = 0; nj < 2; ++nj) { bf[nj][0] = LDB(0, nj, 0); bf[nj][1] = LDB(0, nj, 1); }
        stA(t1, 1);
        SYNC_IN();
        __builtin_amdgcn_s_setprio(1); MMQ(0, 0); __builtin_amdgcn_s_setprio(0);
        SYNC_OUT();

        // ---- P2: read bf[2-3]; stage B(T1)h1
#pragma unroll
        for (int nj = 2; nj < 4; ++nj) { bf[nj][0] = LDB(0, nj, 0); bf[nj][1] = LDB(0, nj, 1); }
        stB(t1, 1);
        SYNC_IN();
        __builtin_amdgcn_s_setprio(1); MMQ(0, 1); __builtin_amdgcn_s_setprio(0);
        SYNC_OUT();

        // ---- P3: read af[4-7]; stage B(T2)h0
#pragma unroll
        for (int mi = 0; mi < 4; ++mi) { af[mi][0] = LDA(0, mi + 4, 0); af[mi][1] = LDA(0, mi + 4, 1); }
        if (pf) stB(t1 + 1, 0);
        SYNC_IN();
        __builtin_amdgcn_s_setprio(1); MMQ(1, 0); __builtin_amdgcn_s_setprio(0);
        SYNC_OUT();

        // ---- P4: stage B(T2)h1; vmcnt
        if (pf) stB(t1 + 1, 1);
        __builtin_amdgcn_s_barrier();
        __builtin_amdgcn_sched_barrier(0);
        __builtin_amdgcn_s_setprio(1); MMQ(1, 1); __builtin_amdgcn_s_setprio(0);
        if (pf) asm volatile("s_waitcnt vmcnt(4)" ::: "memory");
        else    asm volatile("s_waitcnt vmcnt(0)" ::: "memory");
        SYNC_OUT();

        // ---- P5: read T1 af[0-3], bf[0-1]; stage A(T2)h0
#pragma unroll
        for (int mi = 0; mi < 4; ++mi) { af[mi][0] = LDA(1, mi, 0); af[mi][1] = LDA(1, mi, 1); }
#pragma unroll
        for (int nj = 0; nj < 2; ++nj) { bf[nj][0] = LDB(1, nj, 0); bf[nj][1] = LDB(1, nj, 1); }
        if (pf) stA(t1 + 1, 0);
        SYNC_IN();
        __builtin_amdgcn_s_setprio(1); MMQ(0, 0); __builtin_amdgcn_s_setprio(0);
        SYNC_OUT();

        // ---- P6: read bf[2-3]; stage A(T2)h1
#pragma unroll
        for (int nj = 2; nj < 4; ++nj) { bf[nj][0] = LDB(1, nj, 0); bf[nj][1] = LDB(1, nj, 1); }
        if (pf) stA(t1 + 1, 1);
        SYNC_IN();
        __builtin_amdgcn_s_setprio(1); MMQ(0, 1); __builtin_amdgcn_s_setprio(0);
        SYNC_OUT();

        // ---- P7: read af[4-7]; stage B(T3)h0
#pragma unroll
        for (int mi = 0; mi < 4; ++mi) { af[mi][0] = LDA(1, mi + 4, 0); af[mi][1] = LDA(1, mi + 4, 1); }
        if (pf) stB(t1 + 2, 0);
        SYNC_IN();
        __builtin_amdgcn_s_setprio(1); MMQ(1, 0); __builtin_amdgcn_s_setprio(0);
        SYNC_OUT();

        // ---- P8: stage A(T3)h0; vmcnt; loop
        if (pf) stA(t1 + 2, 0);
        __builtin_amdgcn_s_barrier();
        __builtin_amdgcn_sched_barrier(0);
        __builtin_amdgcn_s_setprio(1); MMQ(1, 1); __builtin_amdgcn_s_setprio(0);
        if (pf) asm volatile("s_waitcnt vmcnt(4)" ::: "memory");
        if (i < NI - 1) SYNC_OUT();
    }

    // epilogue: C/D layout col=lane&15, row=(lane>>4)*4+reg
    float bv[4];
#pragma unroll
    for (int ni = 0; ni < 4; ++ni)
        bv[ni] = bias[colInB + (wc << 6) + (ni << 4) + ml];

#pragma unroll
    for (int mi = 0; mi < 8; ++mi) {
#pragma unroll
        for (int r4 = 0; r4 < 4; ++r4) {
            const int row = rowBase + (wr << 7) + (mi << 4) + (kc << 2) + r4;
            const size_t rowoff = (size_t)row * ldc;
#pragma unroll
            for (int ni = 0; ni < 4; ++ni) {
                const int gcol = colBase + (wc << 6) + (ni << 4) + ml;
                float v = acc[mi][ni][r4] + bv[ni];
                if (MODE == EPI_RELU) v = fmaxf(v, 0.f);
                if (MODE == EPI_RES) {
                    v += res[rowoff + gcol];
                    ((float*)C)[rowoff + gcol] = v;          // f32 output
                } else {
                    ((unsigned short*)C)[rowoff + gcol] = f2b(v);  // bf16
                }
            }
        }
    }
#undef LDA
#undef LDB
#undef MMQ
#undef SYNC_IN
#undef SYNC_OUT
}

// ---------------------------------------------------------------------------
extern "C" void kernel_launch(void* const* d_in, const int* in_sizes, int n_in,
                              void* d_out, int out_size, void* d_ws, size_t ws_size,
                              hipStream_t stream)
{
    const float* x   = (const float*)d_in[0];
    const float* Wq  = (const float*)d_in[1];
    const float* bq  = (const float*)d_in[2];
    const float* Wk  = (const float*)d_in[3];
    const float* bk  = (const float*)d_in[4];
    const float* Wv  = (const float*)d_in[5];
    const float* bv  = (const float*)d_in[6];
    const float* Wo  = (const float*)d_in[7];
    const float* bo  = (const float*)d_in[8];
    const float* W1  = (const float*)d_in[9];
    const float* b1  = (const float*)d_in[10];
    const float* W2  = (const float*)d_in[11];
    const float* b2  = (const float*)d_in[12];
    const float* g1  = (const float*)d_in[13];
    const float* be1 = (const float*)d_in[14];
    const float* g2  = (const float*)d_in[15];
    const float* be2 = (const float*)d_in[16];

    const int N = 65536;

    // ws layout:
    //   [0, 6 MiB)    bf16 weights: Wq,Wk,Wv,Wo (512x512), W1 (2048x512), W2 (512x2048)
    //   [6, 70 MiB)   t64: h -> attnout -> h2   (N x 512 bf16)
    //   [70 MiB, ..)  chunk buffer: qkv [Nc][1536] / ff1 [Nc][2048] bf16
    bf16* Wqb = (bf16*)d_ws;
    bf16* Wkb = Wqb + 262144;
    bf16* Wvb = Wkb + 262144;
    bf16* Wob = Wvb + 262144;
    bf16* W1b = Wob + 262144;
    bf16* W2b = W1b + 1048576;
    const size_t wts_bytes = 6ull * 1024 * 1024;
    bf16* t64 = (bf16*)((char*)d_ws + wts_bytes);
    const size_t t64_bytes = (size_t)N * 512 * 2;   // 64 MiB
    bf16* cb  = (bf16*)((char*)d_ws + wts_bytes + t64_bytes);
    const size_t used = wts_bytes + t64_bytes;
    const size_t avail = ws_size > used ? ws_size - used : 0;
    int Nc = 32768;
    while (Nc > 256 && (size_t)Nc * 4096 > avail) Nc >>= 1;

    float* x2 = (float*)d_out;
    dim3 blk(256);
    dim3 blk5(512);

    // 0. convert weights f32 -> bf16
    cvt_kernel<<<262144 / 2048, blk, 0, stream>>>(Wq, Wqb);
    cvt_kernel<<<262144 / 2048, blk, 0, stream>>>(Wk, Wkb);
    cvt_kernel<<<262144 / 2048, blk, 0, stream>>>(Wv, Wvb);
    cvt_kernel<<<262144 / 2048, blk, 0, stream>>>(Wo, Wob);
    cvt_kernel<<<1048576 / 2048, blk, 0, stream>>>(W1, W1b);
    cvt_kernel<<<1048576 / 2048, blk, 0, stream>>>(W2, W2b);

    // 1. h = LN1(x) -> t64 (bf16)
    ln_kernel<<<N / 4, blk, 0, stream>>>(x, g1, be1, t64);

    // 2+3. per chunk: qkv_c = h_c @ [Wq|Wk|Wv]^T + bias ; attnout_c = attn(qkv_c)
    for (int r0 = 0; r0 < N; r0 += Nc) {
        gemm_bt<EPI_PLAIN><<<dim3(6, Nc / 256), blk5, 0, stream>>>(
            t64 + (size_t)r0 * 512, Wqb, Wkb, Wvb, bq, bk, bv, nullptr,
            cb, 512, 512, 1536);
        attn_kernel<<<Nc / 4, blk, 0, stream>>>(cb, t64 + (size_t)r0 * 512);
    }

    // 4. x2 = x + attnout @ Wo^T + bo   -> d_out (f32)
    gemm_bt<EPI_RES><<<dim3(2, N / 256), blk5, 0, stream>>>(
        t64, Wob, Wob, Wob, bo, bo, bo, x, x2, 512, 512, 512);

    // 5. h2 = LN2(x2) -> t64 (bf16)
    ln_kernel<<<N / 4, blk, 0, stream>>>(x2, g2, be2, t64);

    // 6+7. per chunk: ff1_c = relu(h2_c @ W1^T + b1);
    //      out_c = x2_c + ff1_c @ W2^T + b2  (in-place on d_out, f32)
    for (int r0 = 0; r0 < N; r0 += Nc) {
        gemm_bt<EPI_RELU><<<dim3(8, Nc / 256), blk5, 0, stream>>>(
            t64 + (size_t)r0 * 512, W1b, W1b, W1b, b1, b1, b1, nullptr,
            cb, 512, 2048, 2048);
        gemm_bt<EPI_RES><<<dim3(2, Nc / 256), blk5, 0, stream>>>(
            cb, W2b, W2b, W2b, b2, b2, b2, x2 + (size_t)r0 * 512,
            x2 + (size_t)r0 * 512, 2048, 512, 512);
    }
}